// Round 5
// baseline (43.989 us; speedup 1.0000x reference)
//
#include <hip/hip_runtime.h>
#include <hip/hip_bf16.h>

typedef float  f32x4  __attribute__((ext_vector_type(4)));
typedef __bf16 bf16x8 __attribute__((ext_vector_type(8)));
typedef unsigned int   u32x4 __attribute__((ext_vector_type(4)));
typedef unsigned short u16x4 __attribute__((ext_vector_type(4)));

#define NB 32
#define NA 64
#define NF 128
#define NC 128

// ---------------------------------------------------------------------------
// prep: u[b,a,c] = x[b,a,:] @ W0[0:128, c]
//       v[b,a,c] = x[b,a,:] @ W0[128:256, c] + b0[c]
//       wfrag: W1 in MFMA A-fragment order:
//         wfrag[((kk*8+nf)*64 + lane)*8 + e] = bf16(W1[kk*32+(lane>>4)*8+e][nf*16+(lane&15)])
//       so the main loop loads each fragment as a fully-coalesced 16B/lane.
// ---------------------------------------------------------------------------
__global__ __launch_bounds__(512) void prep_kernel(
    const float* __restrict__ x, const float* __restrict__ W0,
    const float* __restrict__ b0, const float* __restrict__ W1,
    float* __restrict__ u, float* __restrict__ v,
    unsigned short* __restrict__ wfrag)
{
    int blk = blockIdx.x;
    int tid = threadIdx.x;
    if (blk < 256) {
        __shared__ __align__(16) float xs[8 * 128];
        int b = blk >> 3;
        int g = blk & 7;
        if (tid < 256)
            ((f32x4*)xs)[tid] =
                ((const f32x4*)(x + (size_t)(b * NA + g * 8) * NF))[tid];
        __syncthreads();
        int c = tid & 127;
        int h = (tid >> 7) & 1;   // 0 -> u, 1 -> v
        int s = tid >> 8;         // atom sub-group: 4 atoms
        const float* wp = W0 + (size_t)h * 128 * NC + c;
        const float* xp = xs + s * 4 * 128;
        float a0 = 0.f, a1 = 0.f, a2 = 0.f, a3 = 0.f;
        #pragma unroll 8
        for (int f = 0; f < 128; ++f) {
            float w = wp[(size_t)f * NC];
            a0 = fmaf(xp[f],       w, a0);
            a1 = fmaf(xp[128 + f], w, a1);
            a2 = fmaf(xp[256 + f], w, a2);
            a3 = fmaf(xp[384 + f], w, a3);
        }
        int row = b * NA + g * 8 + s * 4;
        if (h == 0) {
            u[(size_t)(row + 0) * NC + c] = a0;
            u[(size_t)(row + 1) * NC + c] = a1;
            u[(size_t)(row + 2) * NC + c] = a2;
            u[(size_t)(row + 3) * NC + c] = a3;
        } else {
            float bb = b0[c];
            v[(size_t)(row + 0) * NC + c] = a0 + bb;
            v[(size_t)(row + 1) * NC + c] = a1 + bb;
            v[(size_t)(row + 2) * NC + c] = a2 + bb;
            v[(size_t)(row + 3) * NC + c] = a3 + bb;
        }
    } else {
        // 4096 threads x 4 consecutive elements of the fragment array
        int idx  = ((blk - 256) * 512 + tid) * 4;  // 0..16383, step 4
        int e0   = idx & 7;                        // 0 or 4
        int lane = (idx >> 3) & 63;
        int frag = idx >> 9;                       // 0..31
        int kk   = frag >> 3;
        int nf   = frag & 7;
        int llo  = lane & 15;
        int lhi  = lane >> 4;
        int n    = nf * 16 + llo;
        int kb   = kk * 32 + lhi * 8 + e0;
        u16x4 o;
        #pragma unroll
        for (int e = 0; e < 4; ++e) {
            float w = W1[(size_t)(kb + e) * NC + n];
            o[e] = __builtin_bit_cast(unsigned short, (__bf16)w);
        }
        *(u16x4*)(wfrag + idx) = o;
    }
}

// ---------------------------------------------------------------------------
// main: block = (batch b, unordered 8x8 atom tile pair (I<=J)), 256 thr.
// LDS holds ONLY the u/v tiles (16 KB). W1 fragments are read from global
// (L2-resident, coalesced 1KB wave-loads). One barrier per block.
// ---------------------------------------------------------------------------
__device__ inline bf16x8 relu_cvt_bf16(f32x4 a, f32x4 b)
{
    bf16x8 r;
    #pragma unroll
    for (int e = 0; e < 4; ++e) {
        r[e]     = (__bf16)fmaxf(a[e], 0.f);
        r[e + 4] = (__bf16)fmaxf(b[e], 0.f);
    }
    return r;
}

__global__ __launch_bounds__(256, 4) void pair_mlp_kernel(
    const float* __restrict__ b1g, const float* __restrict__ u,
    const float* __restrict__ v, const unsigned short* __restrict__ wfrag,
    float* __restrict__ out)
{
    __shared__ __align__(16) float u_s[16 * 128];  // rows 0-7: I, 8-15: J
    __shared__ __align__(16) float v_s[16 * 128];

    int blk = blockIdx.x;
    int b = blk / 36;
    int t = blk % 36;
    int I = 0;
    while (t >= 8 - I) { t -= 8 - I; ++I; }
    int J = I + t;

    int tid = threadIdx.x;

    // ---- stage u/v tiles (16B-chunk XOR swizzle on low 3 chunk bits)
    #pragma unroll
    for (int p = 0; p < 4; ++p) {
        int idx = p * 256 + tid;          // 0..1023
        int arr = idx >> 9;               // 0: u, 1: v
        int rem = idx & 511;
        int row = rem >> 5;               // 0..15
        int c   = rem & 31;               // 16B chunk in 512B row
        int ga  = b * NA + ((row < 8) ? (I * 8 + row) : (J * 8 + (row & 7)));
        const float* src = (arr ? v : u) + (size_t)ga * NC;
        float*       dst = (arr ? v_s : u_s) + row * 128;
        int sc = (c & 24) | ((c ^ row) & 7);
        ((f32x4*)dst)[sc] = ((const f32x4*)src)[c];
    }
    __syncthreads();

    int wave = tid >> 6;
    int lane = tid & 63;
    int llo  = lane & 15;
    int lhi  = lane >> 4;
    int r    = wave * 16 + llo;   // pair-row this lane's B-frag/D-col covers
    int il   = r >> 3;            // i_local
    int jl   = r & 7;             // j_local

    f32x4 acc0[8], acc1[8];
    f32x4 z = {0.f, 0.f, 0.f, 0.f};
    #pragma unroll
    for (int nf = 0; nf < 8; ++nf) { acc0[nf] = z; acc1[nf] = z; }

    const float* uI = u_s + il * 128;
    const float* vI = v_s + il * 128;
    const float* uJ = u_s + (8 + jl) * 128;
    const float* vJ = v_s + (8 + jl) * 128;
    const bf16x8* wf = (const bf16x8*)wfrag;   // frag index: (kk*8+nf)*64+lane

    #pragma unroll
    for (int kk = 0; kk < 4; ++kk) {
        int kc  = kk * 8 + lhi * 2;   // f32 16B-chunk of this lane's k-slice
        int kc1 = kc + 1;
        int sA0 = (kc  & 24) | ((kc  ^ il) & 7);
        int sA1 = (kc1 & 24) | ((kc1 ^ il) & 7);
        int sB0 = (kc  & 24) | ((kc  ^ jl) & 7);
        int sB1 = (kc1 & 24) | ((kc1 ^ jl) & 7);

        f32x4 uIa = ((const f32x4*)uI)[sA0];
        f32x4 uIb = ((const f32x4*)uI)[sA1];
        f32x4 vIa = ((const f32x4*)vI)[sA0];
        f32x4 vIb = ((const f32x4*)vI)[sA1];
        f32x4 uJa = ((const f32x4*)uJ)[sB0];
        f32x4 uJb = ((const f32x4*)uJ)[sB1];
        f32x4 vJa = ((const f32x4*)vJ)[sB0];
        f32x4 vJb = ((const f32x4*)vJ)[sB1];

        bf16x8 h0 = relu_cvt_bf16(uIa + vJa, uIb + vJb);  // h(i,j)
        bf16x8 h1 = relu_cvt_bf16(uJa + vIa, uJb + vIb);  // h(j,i)

        #pragma unroll
        for (int nf = 0; nf < 8; ++nf) {
            bf16x8 w = wf[(kk * 8 + nf) * 64 + lane];
            acc0[nf] = __builtin_amdgcn_mfma_f32_16x16x32_bf16(w, h0, acc0[nf], 0, 0, 0);
            acc1[nf] = __builtin_amdgcn_mfma_f32_16x16x32_bf16(w, h1, acc1[nf], 0, 0, 0);
        }
    }

    // ---- epilogue: n = nf*16 + lhi*4 + e  (consecutive e -> dwordx4 stores)
    int Ig = I * 8 + il;
    int Jg = J * 8 + jl;
    float* p1 = out + ((size_t)b * 4096 + Ig * 64 + Jg) * 128 + lhi * 4;
    float* p2 = out + ((size_t)b * 4096 + Jg * 64 + Ig) * 128 + lhi * 4;
    bool mirror = (I != J);
    #pragma unroll
    for (int nf = 0; nf < 8; ++nf) {
        f32x4 bias = *(const f32x4*)(b1g + nf * 16 + lhi * 4);
        f32x4 val;
        #pragma unroll
        for (int e = 0; e < 4; ++e)
            val[e] = fmaxf(acc0[nf][e] + bias[e], 0.f) +
                     fmaxf(acc1[nf][e] + bias[e], 0.f);
        *(f32x4*)(p1 + nf * 16) = val;
        if (mirror)
            *(f32x4*)(p2 + nf * 16) = val;
    }
}

extern "C" void kernel_launch(void* const* d_in, const int* in_sizes, int n_in,
                              void* d_out, int out_size, void* d_ws, size_t ws_size,
                              hipStream_t stream)
{
    (void)in_sizes; (void)n_in; (void)out_size; (void)ws_size;
    const float* x  = (const float*)d_in[0];
    const float* W0 = (const float*)d_in[1];
    const float* b0 = (const float*)d_in[2];
    const float* W1 = (const float*)d_in[3];
    const float* b1 = (const float*)d_in[4];
    float* out = (float*)d_out;

    float* u = (float*)d_ws;                                 // 1 MB
    float* v = u + (size_t)NB * NA * NC;                     // 1 MB
    unsigned short* wfrag = (unsigned short*)(v + (size_t)NB * NA * NC); // 32 KB

    prep_kernel<<<264, 512, 0, stream>>>(x, W0, b0, W1, u, v, wfrag);
    pair_mlp_kernel<<<32 * 36, 256, 0, stream>>>(b1, u, v, wfrag, out);
}

// Round 6
// 34.959 us; speedup vs baseline: 1.2583x; 1.2583x over previous
//
#include <hip/hip_runtime.h>
#include <hip/hip_bf16.h>

typedef float  f32x4  __attribute__((ext_vector_type(4)));
typedef __bf16 bf16x8 __attribute__((ext_vector_type(8)));
typedef unsigned int   u32x4 __attribute__((ext_vector_type(4)));
typedef unsigned short u16x4 __attribute__((ext_vector_type(4)));

#define NB 32
#define NA 64
#define NF 128
#define NC 128

// ---------------------------------------------------------------------------
// prep (tiny): w0t[c][k'] = bf16(W0[k'][c])            (128 x 256 = 64 KB)
//              w1f frag-order: w1f[((kk*8+nf)*64+lane)*8+e]
//                 = bf16(W1[kk*32+(lane>>4)*8+e][nf*16+(lane&15)])  (32 KB)
// ---------------------------------------------------------------------------
__global__ __launch_bounds__(512) void prep_kernel(
    const float* __restrict__ W0, const float* __restrict__ W1,
    unsigned short* __restrict__ w0t, unsigned short* __restrict__ w1f)
{
    int blk = blockIdx.x, tid = threadIdx.x;
    if (blk < 16) {
        int idx = (blk * 512 + tid) * 4;     // 0..32767
        int c  = idx >> 8;
        int kb = idx & 255;
        u16x4 o;
        #pragma unroll
        for (int e = 0; e < 4; ++e)
            o[e] = __builtin_bit_cast(unsigned short,
                     (__bf16)W0[(size_t)(kb + e) * NC + c]);
        *(u16x4*)(w0t + idx) = o;
    } else {
        int idx = ((blk - 16) * 512 + tid) * 4;  // 0..16383
        int e0   = idx & 7;                      // 0 or 4
        int fl   = idx >> 3;
        int lane = fl & 63;
        int frag = fl >> 6;                      // 0..31
        int kk = frag >> 3, nf = frag & 7;
        int k = kk * 32 + (lane >> 4) * 8 + e0;
        int n = nf * 16 + (lane & 15);
        u16x4 o;
        #pragma unroll
        for (int e = 0; e < 4; ++e)
            o[e] = __builtin_bit_cast(unsigned short,
                     (__bf16)W1[(size_t)(k + e) * NC + n]);
        *(u16x4*)(w1f + idx) = o;
    }
}

__device__ inline bf16x8 cvt2_bf16(f32x4 a, f32x4 b)
{
    bf16x8 r;
    #pragma unroll
    for (int e = 0; e < 4; ++e) { r[e] = (__bf16)a[e]; r[e + 4] = (__bf16)b[e]; }
    return r;
}

__device__ inline bf16x8 relu_cvt_bf16(f32x4 a, f32x4 b)
{
    bf16x8 r;
    #pragma unroll
    for (int e = 0; e < 4; ++e) {
        r[e]     = (__bf16)fmaxf(a[e], 0.f);
        r[e + 4] = (__bf16)fmaxf(b[e], 0.f);
    }
    return r;
}

// ---------------------------------------------------------------------------
// fused: 256 blocks = 32 batches x 8 groups, 512 threads, 128 KB LDS, 1/CU.
// Phase A: stage w0t->LDS (swizzled); hoist W1 frags->128 VGPRs; load x frags.
// Phase B: u/v for all 64 atoms of batch b via MFMA -> u_s/v_s (fp32, swz).
// Phase C: 18 flat wave-tasks (4.5 tile-pairs): h=relu(u_i+v_j) -> MFMA with
//          reg-resident W1 -> bias+relu+sum -> direct stores (+mirror).
// ---------------------------------------------------------------------------
__global__ __launch_bounds__(512, 1) void fused_kernel(
    const float* __restrict__ x, const float* __restrict__ b0g,
    const float* __restrict__ b1g, const unsigned short* __restrict__ w0t,
    const unsigned short* __restrict__ w1f, float* __restrict__ out)
{
    __shared__ __align__(16) unsigned short w0_s[128 * 256]; // 64 KB
    __shared__ __align__(16) float          u_s[64 * 128];   // 32 KB
    __shared__ __align__(16) float          v_s[64 * 128];   // 32 KB

    int blk = blockIdx.x;
    int b = blk >> 3;
    int g = blk & 7;
    int tid  = threadIdx.x;
    int wave = tid >> 6, lane = tid & 63;
    int llo  = lane & 15, lhi = lane >> 4;

    // ---- W1 fragments -> registers (32 coalesced 1KB wave-loads, L2)
    bf16x8 wreg[4][8];
    #pragma unroll
    for (int kk = 0; kk < 4; ++kk)
        #pragma unroll
        for (int nf = 0; nf < 8; ++nf)
            wreg[kk][nf] = ((const bf16x8*)w1f)[(kk * 8 + nf) * 64 + lane];

    // ---- phase-B prologue loads (x A-frags + b0), issued pre-barrier
    int uv = wave >> 2, Mt = wave & 3;
    const float* xrow = x + ((size_t)b * NA + Mt * 16 + llo) * NF;
    f32x4 xa[4][2];
    #pragma unroll
    for (int kk = 0; kk < 4; ++kk) {
        xa[kk][0] = *(const f32x4*)(xrow + kk * 32 + lhi * 8);
        xa[kk][1] = *(const f32x4*)(xrow + kk * 32 + lhi * 8 + 4);
    }
    float bias0[8];
    #pragma unroll
    for (int nt = 0; nt < 8; ++nt) bias0[nt] = b0g[nt * 16 + llo];

    // ---- stage w0t -> w0_s (4096 16B chunks, XOR swizzle low-3 by row)
    #pragma unroll
    for (int p = 0; p < 8; ++p) {
        int chunk = p * 512 + tid;       // 0..4095
        int c  = chunk >> 5;             // row 0..127
        int kc = chunk & 31;             // 16B chunk in 512B row
        int sc = (kc & 24) | ((kc ^ c) & 7);
        ((u32x4*)(w0_s + c * 256))[sc] = ((const u32x4*)(w0t + c * 256))[kc];
    }
    __syncthreads();

    // ---- phase B: this wave computes 16 atoms x 128 ch of u (uv=0) / v (uv=1)
    f32x4 acc[8];
    f32x4 z = {0.f, 0.f, 0.f, 0.f};
    #pragma unroll
    for (int nt = 0; nt < 8; ++nt) acc[nt] = z;
    #pragma unroll
    for (int kk = 0; kk < 4; ++kk) {
        bf16x8 af = cvt2_bf16(xa[kk][0], xa[kk][1]);
        int kcb = uv * 16 + kk * 4 + lhi;   // bf16 16B chunk of k'
        #pragma unroll
        for (int nt = 0; nt < 8; ++nt) {
            int c  = nt * 16 + llo;
            int sc = (kcb & 24) | ((kcb ^ c) & 7);
            bf16x8 bf = ((const bf16x8*)(w0_s + c * 256))[sc];
            acc[nt] = __builtin_amdgcn_mfma_f32_16x16x32_bf16(af, bf, acc[nt], 0, 0, 0);
        }
    }
    {
        float* dst = uv ? v_s : u_s;
        #pragma unroll
        for (int nt = 0; nt < 8; ++nt) {
            f32x4 a = acc[nt];
            if (uv) {
                #pragma unroll
                for (int e = 0; e < 4; ++e) a[e] += bias0[nt];
            }
            int c  = nt * 16 + llo;
            int kc = c >> 2;
            #pragma unroll
            for (int q = 0; q < 4; ++q) {
                int atom = Mt * 16 + lhi * 4 + q;
                int sc = (kc & 24) | ((kc ^ atom) & 7);
                dst[atom * 128 + sc * 4 + (c & 3)] = a[q];
            }
        }
    }
    __syncthreads();

    // ---- phase C: flat wave-tasks; 144 tasks/batch, 18 per block
    for (int s = wave; s < 18; s += 8) {
        int tg = g * 18 + s;          // 0..143
        int t  = tg >> 2;             // pair index 0..35
        int q  = tg & 3;              // wave-quad within the 8x8 pair tile
        int I = 0, tr = t;
        while (tr >= 8 - I) { tr -= 8 - I; ++I; }
        int J = I + tr;

        int r  = q * 16 + llo;        // pair-row within 64
        int il = r >> 3, jl = r & 7;
        int rowI = I * 8 + il;
        int rowJ = J * 8 + jl;
        const float* uI = u_s + rowI * 128;
        const float* vI = v_s + rowI * 128;
        const float* uJ = u_s + rowJ * 128;
        const float* vJ = v_s + rowJ * 128;

        f32x4 acc0[8], acc1[8];
        #pragma unroll
        for (int nf = 0; nf < 8; ++nf) { acc0[nf] = z; acc1[nf] = z; }

        #pragma unroll
        for (int kk = 0; kk < 4; ++kk) {
            int kc  = kk * 8 + lhi * 2;
            int kc1 = kc + 1;
            int sA0 = (kc  & 24) | ((kc  ^ rowI) & 7);
            int sA1 = (kc1 & 24) | ((kc1 ^ rowI) & 7);
            int sB0 = (kc  & 24) | ((kc  ^ rowJ) & 7);
            int sB1 = (kc1 & 24) | ((kc1 ^ rowJ) & 7);

            f32x4 uIa = ((const f32x4*)uI)[sA0];
            f32x4 uIb = ((const f32x4*)uI)[sA1];
            f32x4 vIa = ((const f32x4*)vI)[sA0];
            f32x4 vIb = ((const f32x4*)vI)[sA1];
            f32x4 uJa = ((const f32x4*)uJ)[sB0];
            f32x4 uJb = ((const f32x4*)uJ)[sB1];
            f32x4 vJa = ((const f32x4*)vJ)[sB0];
            f32x4 vJb = ((const f32x4*)vJ)[sB1];

            bf16x8 h0 = relu_cvt_bf16(uIa + vJa, uIb + vJb);  // h(i,j)
            bf16x8 h1 = relu_cvt_bf16(uJa + vIa, uJb + vIb);  // h(j,i)

            #pragma unroll
            for (int nf = 0; nf < 8; ++nf) {
                acc0[nf] = __builtin_amdgcn_mfma_f32_16x16x32_bf16(
                    wreg[kk][nf], h0, acc0[nf], 0, 0, 0);
                acc1[nf] = __builtin_amdgcn_mfma_f32_16x16x32_bf16(
                    wreg[kk][nf], h1, acc1[nf], 0, 0, 0);
            }
        }

        // epilogue: n = nf*16 + lhi*4 + e
        float* p1 = out + ((size_t)b * 4096 + rowI * 64 + rowJ) * 128 + lhi * 4;
        float* p2 = out + ((size_t)b * 4096 + rowJ * 64 + rowI) * 128 + lhi * 4;
        bool mirror = (I != J);
        #pragma unroll
        for (int nf = 0; nf < 8; ++nf) {
            f32x4 bias = *(const f32x4*)(b1g + nf * 16 + lhi * 4);
            f32x4 val;
            #pragma unroll
            for (int e = 0; e < 4; ++e)
                val[e] = fmaxf(acc0[nf][e] + bias[e], 0.f) +
                         fmaxf(acc1[nf][e] + bias[e], 0.f);
            *(f32x4*)(p1 + nf * 16) = val;
            if (mirror)
                *(f32x4*)(p2 + nf * 16) = val;
        }
    }
}

extern "C" void kernel_launch(void* const* d_in, const int* in_sizes, int n_in,
                              void* d_out, int out_size, void* d_ws, size_t ws_size,
                              hipStream_t stream)
{
    (void)in_sizes; (void)n_in; (void)out_size; (void)ws_size;
    const float* x  = (const float*)d_in[0];
    const float* W0 = (const float*)d_in[1];
    const float* b0 = (const float*)d_in[2];
    const float* W1 = (const float*)d_in[3];
    const float* b1 = (const float*)d_in[4];
    float* out = (float*)d_out;

    unsigned short* w0t = (unsigned short*)d_ws;          // 64 KB
    unsigned short* w1f = w0t + 128 * 256;                // 32 KB

    prep_kernel<<<24, 512, 0, stream>>>(W0, W1, w0t, w1f);
    fused_kernel<<<NB * 8, 512, 0, stream>>>(x, b0, b1, w0t, w1f, out);
}

// Round 7
// 32.326 us; speedup vs baseline: 1.3608x; 1.0814x over previous
//
#include <hip/hip_runtime.h>
#include <hip/hip_bf16.h>

typedef float    f32x4 __attribute__((ext_vector_type(4)));
typedef _Float16 f16x8 __attribute__((ext_vector_type(8)));
typedef unsigned int   u32x4 __attribute__((ext_vector_type(4)));
typedef unsigned short u16x4 __attribute__((ext_vector_type(4)));

#define NB 32
#define NA 64
#define NF 128
#define NC 128

// ---------------------------------------------------------------------------
// prep: u[b,a,c] = fp16( x[b,a,:] @ W0[0:128, c] )
//       v[b,a,c] = fp16( x[b,a,:] @ W0[128:256, c] + b0[c] )
//       w1f: W1 in fp16 MFMA A-fragment order:
//         w1f[((kk*8+nf)*64+lane)*8+e] = f16(W1[kk*32+(lane>>4)*8+e][nf*16+(lane&15)])
// ---------------------------------------------------------------------------
__global__ __launch_bounds__(512) void prep_kernel(
    const float* __restrict__ x, const float* __restrict__ W0,
    const float* __restrict__ b0, const float* __restrict__ W1,
    _Float16* __restrict__ u, _Float16* __restrict__ v,
    _Float16* __restrict__ w1f)
{
    int blk = blockIdx.x;
    int tid = threadIdx.x;
    if (blk < 256) {
        __shared__ __align__(16) float xs[8 * 128];
        int b = blk >> 3;
        int g = blk & 7;
        if (tid < 256)
            ((f32x4*)xs)[tid] =
                ((const f32x4*)(x + (size_t)(b * NA + g * 8) * NF))[tid];
        __syncthreads();
        int c = tid & 127;
        int h = (tid >> 7) & 1;   // 0 -> u, 1 -> v
        int s = tid >> 8;         // atom sub-group: 4 atoms
        const float* wp = W0 + (size_t)h * 128 * NC + c;
        const float* xp = xs + s * 4 * 128;
        float a0 = 0.f, a1 = 0.f, a2 = 0.f, a3 = 0.f;
        #pragma unroll 8
        for (int f = 0; f < 128; ++f) {
            float w = wp[(size_t)f * NC];
            a0 = fmaf(xp[f],       w, a0);
            a1 = fmaf(xp[128 + f], w, a1);
            a2 = fmaf(xp[256 + f], w, a2);
            a3 = fmaf(xp[384 + f], w, a3);
        }
        int row = b * NA + g * 8 + s * 4;
        if (h == 0) {
            u[(size_t)(row + 0) * NC + c] = (_Float16)a0;
            u[(size_t)(row + 1) * NC + c] = (_Float16)a1;
            u[(size_t)(row + 2) * NC + c] = (_Float16)a2;
            u[(size_t)(row + 3) * NC + c] = (_Float16)a3;
        } else {
            float bb = b0[c];
            v[(size_t)(row + 0) * NC + c] = (_Float16)(a0 + bb);
            v[(size_t)(row + 1) * NC + c] = (_Float16)(a1 + bb);
            v[(size_t)(row + 2) * NC + c] = (_Float16)(a2 + bb);
            v[(size_t)(row + 3) * NC + c] = (_Float16)(a3 + bb);
        }
    } else {
        int idx  = ((blk - 256) * 512 + tid) * 4;  // 0..16383, step 4
        int e0   = idx & 7;                        // 0 or 4
        int fl   = idx >> 3;
        int lane = fl & 63;
        int frag = fl >> 6;                        // 0..31
        int kk = frag >> 3, nf = frag & 7;
        int k = kk * 32 + (lane >> 4) * 8 + e0;
        int n = nf * 16 + (lane & 15);
        u16x4 o;
        #pragma unroll
        for (int e = 0; e < 4; ++e) {
            _Float16 w = (_Float16)W1[(size_t)(k + e) * NC + n];
            o[e] = __builtin_bit_cast(unsigned short, w);
        }
        *(u16x4*)(w1f + idx) = o;
    }
}

// ---------------------------------------------------------------------------
// main: block = (batch b, unordered 8x8 atom tile pair (I<=J)), 256 thr.
// All fp16: u/v tiles (4KB each) + W1 frag-order (32KB) in LDS; h = relu(u+v)
// via packed-f16 add/max; mfma_f32_16x16x32_f16; direct fp32 stores.
// ---------------------------------------------------------------------------
__global__ __launch_bounds__(256, 3) void pair_mlp_kernel(
    const float* __restrict__ b1g, const _Float16* __restrict__ u,
    const _Float16* __restrict__ v, const _Float16* __restrict__ w1f,
    float* __restrict__ out)
{
    __shared__ __align__(16) _Float16 u_s[16 * 128];   // 4 KB (rows 0-7: I, 8-15: J)
    __shared__ __align__(16) _Float16 v_s[16 * 128];   // 4 KB
    __shared__ __align__(16) _Float16 w_s[32 * 64 * 8]; // 32 KB, frag-major

    int blk = blockIdx.x;
    int b = blk / 36;
    int t = blk % 36;
    int I = 0;
    while (t >= 8 - I) { t -= 8 - I; ++I; }
    int J = I + t;

    int tid = threadIdx.x;

    // ---- stage u/v tiles: 256 chunks of 16B each array, all contiguous
    {
        int row = tid >> 4;            // 0..15
        int c   = tid & 15;            // 16B chunk within 256B row
        int ga  = b * NA + ((row < 8) ? (I * 8 + row) : (J * 8 + (row & 7)));
        ((u32x4*)u_s)[tid] = ((const u32x4*)(u + (size_t)ga * NC))[c];
        ((u32x4*)v_s)[tid] = ((const u32x4*)(v + (size_t)ga * NC))[c];
    }
    // ---- stage W1 frags: 2048 contiguous 16B chunks
    #pragma unroll
    for (int p = 0; p < 8; ++p)
        ((u32x4*)w_s)[p * 256 + tid] = ((const u32x4*)w1f)[p * 256 + tid];
    __syncthreads();

    int wave = tid >> 6;
    int lane = tid & 63;
    int llo  = lane & 15;
    int lhi  = lane >> 4;
    int r    = wave * 16 + llo;   // pair-row this lane's B-frag/D-col covers
    int il   = r >> 3;            // i_local
    int jl   = r & 7;             // j_local

    f32x4 acc0[8], acc1[8];
    f32x4 z = {0.f, 0.f, 0.f, 0.f};
    #pragma unroll
    for (int nf = 0; nf < 8; ++nf) { acc0[nf] = z; acc1[nf] = z; }

    const f16x8* uI = (const f16x8*)(u_s + il * 128);
    const f16x8* vI = (const f16x8*)(v_s + il * 128);
    const f16x8* uJ = (const f16x8*)(u_s + (8 + jl) * 128);
    const f16x8* vJ = (const f16x8*)(v_s + (8 + jl) * 128);
    const f16x8* wf = (const f16x8*)w_s;

    #pragma unroll
    for (int kk = 0; kk < 4; ++kk) {
        int kc = kk * 4 + lhi;        // 16B chunk of this lane's k-slice

        f16x8 uIv = uI[kc];
        f16x8 vIv = vI[kc];
        f16x8 uJv = uJ[kc];
        f16x8 vJv = vJ[kc];

        f16x8 s0 = uIv + vJv;         // h(i,j) pre-relu
        f16x8 s1 = uJv + vIv;         // h(j,i) pre-relu
        f16x8 h0, h1;
        #pragma unroll
        for (int e = 0; e < 8; ++e) {
            h0[e] = s0[e] < (_Float16)0 ? (_Float16)0 : s0[e];
            h1[e] = s1[e] < (_Float16)0 ? (_Float16)0 : s1[e];
        }

        #pragma unroll
        for (int nf = 0; nf < 8; ++nf) {
            f16x8 w = wf[(kk * 8 + nf) * 64 + lane];
            acc0[nf] = __builtin_amdgcn_mfma_f32_16x16x32_f16(w, h0, acc0[nf], 0, 0, 0);
            acc1[nf] = __builtin_amdgcn_mfma_f32_16x16x32_f16(w, h1, acc1[nf], 0, 0, 0);
        }
    }

    // ---- epilogue: n = nf*16 + lhi*4 + e  (consecutive e -> dwordx4 stores)
    int Ig = I * 8 + il;
    int Jg = J * 8 + jl;
    float* p1 = out + ((size_t)b * 4096 + Ig * 64 + Jg) * 128 + lhi * 4;
    float* p2 = out + ((size_t)b * 4096 + Jg * 64 + Ig) * 128 + lhi * 4;
    bool mirror = (I != J);
    #pragma unroll
    for (int nf = 0; nf < 8; ++nf) {
        f32x4 bias = *(const f32x4*)(b1g + nf * 16 + lhi * 4);
        f32x4 val;
        #pragma unroll
        for (int e = 0; e < 4; ++e)
            val[e] = fmaxf(acc0[nf][e] + bias[e], 0.f) +
                     fmaxf(acc1[nf][e] + bias[e], 0.f);
        *(f32x4*)(p1 + nf * 16) = val;
        if (mirror)
            *(f32x4*)(p2 + nf * 16) = val;
    }
}

extern "C" void kernel_launch(void* const* d_in, const int* in_sizes, int n_in,
                              void* d_out, int out_size, void* d_ws, size_t ws_size,
                              hipStream_t stream)
{
    (void)in_sizes; (void)n_in; (void)out_size; (void)ws_size;
    const float* x  = (const float*)d_in[0];
    const float* W0 = (const float*)d_in[1];
    const float* b0 = (const float*)d_in[2];
    const float* W1 = (const float*)d_in[3];
    const float* b1 = (const float*)d_in[4];
    float* out = (float*)d_out;

    _Float16* u   = (_Float16*)d_ws;                       // 0.5 MB
    _Float16* v   = u + (size_t)NB * NA * NC;              // 0.5 MB
    _Float16* w1f = v + (size_t)NB * NA * NC;              // 32 KB

    prep_kernel<<<264, 512, 0, stream>>>(x, W0, b0, W1, u, v, w1f);
    pair_mlp_kernel<<<32 * 36, 256, 0, stream>>>(b1, u, v, w1f, out);
}